// Round 7
// baseline (136.164 us; speedup 1.0000x reference)
//
#include <hip/hip_runtime.h>

typedef __attribute__((ext_vector_type(8))) short short8;
typedef __attribute__((ext_vector_type(4))) float f32x4;

#define C_DIM 128
#define K_CODES 1024
#define TOT 8388608   // 16*128*64*64
#define NBLK 512      // 128 contiguous pixels per block

__device__ __forceinline__ unsigned int f2bf1(float f) {
  unsigned int u = __float_as_uint(f);
  return (u + 0x7FFFu + ((u >> 16) & 1u)) >> 16;   // RNE fp32->bf16
}
__device__ __forceinline__ unsigned int f2bf2(float lo, float hi) {
  return f2bf1(lo) | (f2bf1(hi) << 16);
}

union U16x8 { uint4 u; short8 s; };

// ---- P: bf16 codebook + (1 + ||e||^2) + zero used ----
// Grid 128: 32768 threads x (16B read / 8B write) == K*C exactly (R8 lesson).
__global__ void prep_kernel(const float* __restrict__ cb,
                            unsigned short* __restrict__ ebf,
                            float* __restrict__ nsq1,
                            int* __restrict__ used) {
  int gid = blockIdx.x * 256 + threadIdx.x;     // 128 blocks * 256 = 32768 = K*C/4
  const float4 v = ((const float4*)cb)[gid];    // 32768*16B = 512KB = cb size
  uint2 pk;
  pk.x = f2bf2(v.x, v.y);
  pk.y = f2bf2(v.z, v.w);
  ((uint2*)ebf)[gid] = pk;                      // 32768*8B = 256KB = ebf size
  if (gid < K_CODES) {
    float s = 0.f;
    #pragma unroll 8
    for (int c = 0; c < C_DIM; ++c) { float w = cb[gid * C_DIM + c]; s += w * w; }
    nsq1[gid] = 1.0f + s;      // +1 keeps d positive -> u32-monotone float bits
    used[gid] = 0;
  }
}

// ---- M: block = 128 px; 4 waves = px-half (ph) x code-half (kh) ----
// R6 post-mortem: swizzle verified (BANK_CONFLICT 2.1M -> 0) but vq got
// SLOWER (43.5 vs <42): conflicts weren't the critical path, and the
// kq-split quadrupled A-prologue z redundancy. R13: (a) revert to the
// proven R0 4-wave geometry (2x A redundancy, 16 MFMA / 8 ds_read per
// chunk/wave) KEEPING the measured-conflict-free swizzle; (b) loss from
// the MFMA distance itself: d_hat = 1 + ||e||^2 - 2z.e (C-init does it),
// so loss_px = (d_hat_min - 1) + ||z||^2 with ||z||^2 accumulated in f32
// during the A-prologue (kh==0 waves only -> exact single count) and
// d_hat_min recovered from the argmin key (as_float(key & ~1023) - 1).
// Epilogue no longer re-reads z: -134MB L3 traffic, -64 loads/thread in
// the serial post-argmin phase. Truncation bias (2^-13/px over C=128
// elems) and bf16-dot noise ~1e-4 << 2.5e-2 threshold.
// Epilogue coherence: plain used[]=1 + lossp store + separate finalize
// (R3/R4 proved in-kernel cross-XCD coherence costs ~us/block).
__global__ __launch_bounds__(256, 3)
void vq_main(const float* __restrict__ zin,
             const unsigned short* __restrict__ ebf,
             const float* __restrict__ nsq1,
             int* __restrict__ used, float* __restrict__ lossp,
             float* __restrict__ out) {
  __shared__ __align__(16) uint4 bG[2][1024];   // 2 x 16KB: 64-code chunks
  __shared__ float nsq_s[K_CODES];
  __shared__ unsigned int mergeK[128][2];
  __shared__ int   widx[128];
  __shared__ float wsum[4];

  const int t  = threadIdx.x;
  const int L  = t & 63;
  const int wv = t >> 6;        // wave 0..3
  const int ph = wv >> 1;       // pixel half: px [ph*64, ph*64+64)
  const int kh = wv & 1;        // code half: jj tiles {kh*2, kh*2+1}
  const int q  = L >> 4;        // lane quad
  const int nL = L & 15;

  const int bb = blockIdx.x >> 5;          // batch 0..15
  const int hg = blockIdx.x & 31;          // 128-px group
  const int zoff = bb * (C_DIM * 4096) + hg * 128;   // + c*4096 + p

  for (int i = t; i < K_CODES; i += 256) nsq_s[i] = nsq1[i];

  // ---- A fragments straight from global, packed bf16(-2z) in-register;
  // f32 ||z||^2 partial accumulated on the fly (exact, pre-bf16).
  short8 afrag[16];
  float zsq = 0.f;
  #pragma unroll
  for (int mt = 0; mt < 4; ++mt) {
    const int wcol = ph * 64 + mt * 16 + nL;
    #pragma unroll
    for (int ks = 0; ks < 4; ++ks) {
      float v[8];
      #pragma unroll
      for (int u = 0; u < 8; ++u) {
        v[u] = zin[zoff + (ks * 32 + q * 8 + u) * 4096 + wcol];
        zsq += v[u] * v[u];
      }
      U16x8 pk;
      pk.u.x = f2bf2(-2.f * v[0], -2.f * v[1]);
      pk.u.y = f2bf2(-2.f * v[2], -2.f * v[3]);
      pk.u.z = f2bf2(-2.f * v[4], -2.f * v[5]);
      pk.u.w = f2bf2(-2.f * v[6], -2.f * v[7]);
      afrag[mt * 4 + ks] = pk.s;
    }
  }
  zsq = (kh == 0) ? zsq : 0.f;   // each z elem read by kh=0 and kh=1: count once

  // ---- staging thread roles (256 threads x 4 granules / chunk), swizzled.
  // Swizzle (R6-verified, BANK_CONFLICT==0): slot within 64-entry subtile =
  // (rl>>1)*8 + ((rl0^ks0)<<2) + ((q ^ rl[2:1])&3), bijective per subtile;
  // every 8-lane phase of writes AND reads covers 8 distinct bank-quads.
  const uint4* __restrict__ ebv = (const uint4*)ebf;   // granule view, row=16
  const int nLw = t >> 4;        // row-within-group 0..15
  const int oct = t & 15;        // granule-within-row
  const int sks = oct >> 2, sq = oct & 3;
  const int swbase = (nLw >> 1) * 8 + (((nLw ^ sks) & 1) << 2)
                   + ((sq ^ (nLw >> 1)) & 3);

  // stage chunk 0
  #pragma unroll
  for (int p = 0; p < 4; ++p)
    bG[0][p * 256 + sks * 64 + swbase] = ebv[(p * 16 + nLw) * 16 + oct];
  __syncthreads();

  // read-side swizzled slot offsets (ks even -> sA, ks odd -> sB)
  const int rdq = (q ^ (nL >> 1)) & 3;
  const int sA = (nL >> 1) * 8 + ((nL & 1) << 2) + rdq;
  const int sB = (nL >> 1) * 8 + (((nL ^ 1) & 1) << 2) + rdq;

  unsigned int kmin[16];
  #pragma unroll
  for (int i = 0; i < 16; ++i) kmin[i] = 0xFFFFFFFFu;

  // ---- K loop: 16 chunks; this wave consumes its 2 jj-tiles (32 codes)
  #pragma unroll 1
  for (int ch = 0; ch < 16; ++ch) {
    const int cur = ch & 1;
    if (ch < 15) {                               // stage next chunk into !cur
      #pragma unroll
      for (int p = 0; p < 4; ++p)
        bG[cur ^ 1][p * 256 + sks * 64 + swbase] =
            ebv[((ch + 1) * 64 + p * 16 + nLw) * 16 + oct];
    }
    const short8* bp = (const short8*)bG[cur];
    #pragma unroll
    for (int j2 = 0; j2 < 2; ++j2) {
      const int jj = kh * 2 + j2;
      const int row = ch * 64 + jj * 16 + nL;    // this lane's code
      short8 b0 = bp[jj * 256 +   0 + sA];
      short8 b1 = bp[jj * 256 +  64 + sB];
      short8 b2 = bp[jj * 256 + 128 + sA];
      short8 b3 = bp[jj * 256 + 192 + sB];
      const float nv = nsq_s[row];
      f32x4 a0 = {nv, nv, nv, nv};
      f32x4 a1 = {nv, nv, nv, nv};
      f32x4 a2 = {nv, nv, nv, nv};
      f32x4 a3 = {nv, nv, nv, nv};
      a0 = __builtin_amdgcn_mfma_f32_16x16x32_bf16(afrag[0],  b0, a0, 0, 0, 0);
      a1 = __builtin_amdgcn_mfma_f32_16x16x32_bf16(afrag[4],  b0, a1, 0, 0, 0);
      a2 = __builtin_amdgcn_mfma_f32_16x16x32_bf16(afrag[8],  b0, a2, 0, 0, 0);
      a3 = __builtin_amdgcn_mfma_f32_16x16x32_bf16(afrag[12], b0, a3, 0, 0, 0);
      a0 = __builtin_amdgcn_mfma_f32_16x16x32_bf16(afrag[1],  b1, a0, 0, 0, 0);
      a1 = __builtin_amdgcn_mfma_f32_16x16x32_bf16(afrag[5],  b1, a1, 0, 0, 0);
      a2 = __builtin_amdgcn_mfma_f32_16x16x32_bf16(afrag[9],  b1, a2, 0, 0, 0);
      a3 = __builtin_amdgcn_mfma_f32_16x16x32_bf16(afrag[13], b1, a3, 0, 0, 0);
      a0 = __builtin_amdgcn_mfma_f32_16x16x32_bf16(afrag[2],  b2, a0, 0, 0, 0);
      a1 = __builtin_amdgcn_mfma_f32_16x16x32_bf16(afrag[6],  b2, a1, 0, 0, 0);
      a2 = __builtin_amdgcn_mfma_f32_16x16x32_bf16(afrag[10], b2, a2, 0, 0, 0);
      a3 = __builtin_amdgcn_mfma_f32_16x16x32_bf16(afrag[14], b2, a3, 0, 0, 0);
      a0 = __builtin_amdgcn_mfma_f32_16x16x32_bf16(afrag[3],  b3, a0, 0, 0, 0);
      a1 = __builtin_amdgcn_mfma_f32_16x16x32_bf16(afrag[7],  b3, a1, 0, 0, 0);
      a2 = __builtin_amdgcn_mfma_f32_16x16x32_bf16(afrag[11], b3, a2, 0, 0, 0);
      a3 = __builtin_amdgcn_mfma_f32_16x16x32_bf16(afrag[15], b3, a3, 0, 0, 0);
      const unsigned int rowc = (unsigned int)row;
      #pragma unroll
      for (int r = 0; r < 4; ++r) {
        unsigned int k0 = (__float_as_uint(a0[r]) & 0xFFFFFC00u) | rowc;
        if (k0 < kmin[r]) kmin[r] = k0;
        unsigned int k1 = (__float_as_uint(a1[r]) & 0xFFFFFC00u) | rowc;
        if (k1 < kmin[4 + r]) kmin[4 + r] = k1;
        unsigned int k2 = (__float_as_uint(a2[r]) & 0xFFFFFC00u) | rowc;
        if (k2 < kmin[8 + r]) kmin[8 + r] = k2;
        unsigned int k3 = (__float_as_uint(a3[r]) & 0xFFFFFC00u) | rowc;
        if (k3 < kmin[12 + r]) kmin[12 + r] = k3;
      }
    }
    __syncthreads();   // next-chunk writes visible; cur free for re-stage
  }

  // ---- in-wave butterfly u32-min over the 16 code-lanes of each quad
  #pragma unroll
  for (int m = 1; m <= 8; m <<= 1) {
    #pragma unroll
    for (int i = 0; i < 16; ++i) {
      unsigned int o = (unsigned int)__shfl_xor((int)kmin[i], m, 64);
      if (o < kmin[i]) kmin[i] = o;
    }
  }
  if (nL == 0) {
    #pragma unroll
    for (int mt = 0; mt < 4; ++mt)
      #pragma unroll
      for (int r = 0; r < 4; ++r)
        mergeK[ph * 64 + mt * 16 + q * 4 + r][kh] = kmin[mt * 4 + r];
  }
  __syncthreads();

  // ---- cross-half merge + per-pixel distance from the winning key
  float dval = 0.f;
  if (t < 128) {
    unsigned int b = min(mergeK[t][0], mergeK[t][1]);
    int bi = (int)(b & 1023u);
    widx[t] = bi;
    used[bi] = 1;   // benign same-value race; kernel boundary = coherence
    dval = __uint_as_float(b & 0xFFFFFC00u) - 1.0f;   // d_hat_min - 1
  }
  __syncthreads();

  // ---- gather bf16 e-row -> out only (NO z re-read; loss is algebraic)
  {
    const int p = t & 127, cg = t >> 7;    // 2 channel halves x 64 ch
    const int idx = widx[p];
    const uint4* erow = ebv + idx * 16 + cg * 8;
    const int obase = zoff + cg * 64 * 4096 + p;
    #pragma unroll
    for (int i = 0; i < 8; ++i) {
      uint4 g = erow[i];
      const unsigned int wrd[4] = {g.x, g.y, g.z, g.w};
      #pragma unroll
      for (int half = 0; half < 4; ++half) {
        float e0 = __uint_as_float(wrd[half] << 16);
        float e1 = __uint_as_float(wrd[half] & 0xFFFF0000u);
        int off = obase + (i * 8 + half * 2) * 4096;
        out[off] = e0;                     // lanes over p -> 256B contiguous
        out[off + 4096] = e1;
      }
    }
  }

  // ---- loss partial: sum(zsq) over kh==0 waves + sum(dval) over 128 px
  float lsum = zsq + dval;
  #pragma unroll
  for (int o = 32; o > 0; o >>= 1) lsum += __shfl_down(lsum, o, 64);
  if (L == 0) wsum[wv] = lsum;
  __syncthreads();
  if (t == 0)
    lossp[blockIdx.x] = (wsum[0] + wsum[1]) + (wsum[2] + wsum[3]);
}

// ---- F: usage count + loss finalize ----
__global__ void finalize_kernel(const int* __restrict__ used,
                                const float* __restrict__ lossp,
                                float* __restrict__ out2) {
  __shared__ int   redi[256];
  __shared__ float redf[256];
  int t = threadIdx.x;
  int s = 0;
  for (int i = t; i < K_CODES; i += 256) s += (used[i] != 0) ? 1 : 0;
  float ls = 0.f;
  for (int i = t; i < NBLK; i += 256) ls += lossp[i];
  redi[t] = s; redf[t] = ls;
  __syncthreads();
  for (int o = 128; o > 0; o >>= 1) {
    if (t < o) { redi[t] += redi[t + o]; redf[t] += redf[t + o]; }
    __syncthreads();
  }
  if (t == 0) {
    out2[0] = 1.25f * redf[0] / (float)TOT;  // (1+0.25)*MSE
    out2[1] = (float)redi[0] / 1024.0f;
  }
}

extern "C" void kernel_launch(void* const* d_in, const int* in_sizes, int n_in,
                              void* d_out, int out_size, void* d_ws, size_t ws_size,
                              hipStream_t stream) {
  const float* z  = (const float*)d_in[0];
  const float* cb = (const float*)d_in[1];
  float* out = (float*)d_out;
  char* ws = (char*)d_ws;
  unsigned short* ebf = (unsigned short*)ws;          // 262144 B
  float* nsq1  = (float*)(ws + 262144);               // 4096 B
  int*   used  = (int*)(ws + 266240);                 // 4096 B
  float* lossp = (float*)(ws + 270336);               // 2048 B (per-block partials)

  hipLaunchKernelGGL(prep_kernel, dim3(128), dim3(256), 0, stream,
                     cb, ebf, nsq1, used);
  hipLaunchKernelGGL(vq_main, dim3(NBLK), dim3(256), 0, stream,
                     z, ebf, nsq1, used, lossp, out);
  hipLaunchKernelGGL(finalize_kernel, dim3(1), dim3(256), 0, stream,
                     used, lossp, out + TOT);
}

// Round 9
// 113.314 us; speedup vs baseline: 1.2017x; 1.2017x over previous
//
#include <hip/hip_runtime.h>

typedef __attribute__((ext_vector_type(8))) short short8;
typedef __attribute__((ext_vector_type(4))) float f32x4;

#define C_DIM 128
#define K_CODES 1024
#define TOT 8388608   // 16*128*64*64
#define NBLK 512      // 128 contiguous pixels per block

__device__ __forceinline__ unsigned int f2bf1(float f) {
  unsigned int u = __float_as_uint(f);
  return (u + 0x7FFFu + ((u >> 16) & 1u)) >> 16;   // RNE fp32->bf16
}
__device__ __forceinline__ unsigned int f2bf2(float lo, float hi) {
  return f2bf1(lo) | (f2bf1(hi) << 16);
}

union U16x8 { uint4 u; short8 s; };

// ---- P: bf16 codebook + (1 + ||e||^2) + zero used ----
// R8(final): vectorized convert (verified R3-R7) + ||e||^2 via 32-lane
// shuffle butterfly over the SAME float4s already in registers — removes
// the old 1024-thread x 128 uncoalesced scalar re-read (serial tail,
// ~10us: consecutive lanes strided 512B = 64 lines/wave-instr).
// 32 threads/code-row x float4 = 128 ch exactly; masks 1..16 reduce within
// 32-lane halves of the wave; lanes t%32==0 hold row sums (rows 2r, 2r+1).
// Summation order changes vs sequential — argmin flips only on near-ties,
// and codebook scale (uniform +-1/K) bounds any flip's z_q delta by ~4e-3
// elementwise << 2.5e-2 threshold.
__global__ void prep_kernel(const float* __restrict__ cb,
                            unsigned short* __restrict__ ebf,
                            float* __restrict__ nsq1,
                            int* __restrict__ used) {
  int gid = blockIdx.x * 256 + threadIdx.x;     // 128 blocks * 256 = 32768 = K*C/4
  const float4 v = ((const float4*)cb)[gid];    // 32768*16B = 512KB = cb size
  uint2 pk;
  pk.x = f2bf2(v.x, v.y);
  pk.y = f2bf2(v.z, v.w);
  ((uint2*)ebf)[gid] = pk;                      // 32768*8B = 256KB = ebf size
  float s = v.x * v.x + v.y * v.y + v.z * v.z + v.w * v.w;
  #pragma unroll
  for (int m = 1; m <= 16; m <<= 1) s += __shfl_xor(s, m, 64);
  if ((threadIdx.x & 31) == 0)
    nsq1[gid >> 5] = 1.0f + s;   // +1 keeps d positive -> u32-monotone bits
  if (gid < K_CODES) used[gid] = 0;
}

// ---- M: block = 128 px; wave = 64 px x 512 codes (half-split); B via LDS ----
// REVERTED byte-identical to the R0-proven kernel (116.0us total, vq 38-41us).
// Session ledger: fused-finalize (+26us: RELEASE=per-block L2 flush), 8-wave
// occupancy (parity: LDS traffic doubled as occupancy doubled), XOR swizzle
// (conflicts 2.1M->0 but NOT critical path), algebraic loss (+17us, write
// amplification 33->86MB) — all bounced off this plateau. vq is latency-
// bound at ~4x its 67MB/6.4TBps compulsory floor; structural changes that
// touch the proven phase order have all regressed.
__global__ __launch_bounds__(256, 3)
void vq_main(const float* __restrict__ zin, const float* __restrict__ cb,
             const unsigned short* __restrict__ ebf,
             const float* __restrict__ nsq1,
             int* __restrict__ used, float* __restrict__ lossp,
             float* __restrict__ out) {
  __shared__ __align__(16) uint4 bG[2][1024];   // 2 x 16KB: 64-code chunks
  __shared__ float nsq_s[K_CODES];
  __shared__ unsigned int mergeK[128][2];
  __shared__ int   widx[128];
  __shared__ float wsum[4];

  const int t  = threadIdx.x;
  const int L  = t & 63;
  const int wv = t >> 6;        // wave 0..3
  const int ph = wv >> 1;       // pixel half: px [ph*64, ph*64+64)
  const int kh = wv & 1;        // code half: jj tiles {kh*2, kh*2+1}
  const int q  = L >> 4;        // lane quad
  const int nL = L & 15;

  const int bb = blockIdx.x >> 5;          // batch 0..15
  const int hg = blockIdx.x & 31;          // 128-px group
  const int zoff = bb * (C_DIM * 4096) + hg * 128;   // + c*4096 + p

  for (int i = t; i < K_CODES; i += 256) nsq_s[i] = nsq1[i];

  // ---- A fragments straight from global, packed bf16(-2z) in-register
  short8 afrag[16];
  #pragma unroll
  for (int mt = 0; mt < 4; ++mt) {
    const int wcol = ph * 64 + mt * 16 + nL;
    #pragma unroll
    for (int ks = 0; ks < 4; ++ks) {
      float v[8];
      #pragma unroll
      for (int u = 0; u < 8; ++u)
        v[u] = zin[zoff + (ks * 32 + q * 8 + u) * 4096 + wcol];
      U16x8 pk;
      pk.u.x = f2bf2(-2.f * v[0], -2.f * v[1]);
      pk.u.y = f2bf2(-2.f * v[2], -2.f * v[3]);
      pk.u.z = f2bf2(-2.f * v[4], -2.f * v[5]);
      pk.u.w = f2bf2(-2.f * v[6], -2.f * v[7]);
      afrag[mt * 4 + ks] = pk.s;
    }
  }

  // ---- staging thread roles (contiguous 1KB per wave-instruction)
  const uint4* __restrict__ ebv = (const uint4*)ebf;   // granule view, row=16
  const int nLw = t >> 4;        // row-within-group 0..15
  const int oct = t & 15;        // granule-within-row
  const int sks = oct >> 2, sq = oct & 3;

  // stage chunk 0
  #pragma unroll
  for (int p = 0; p < 4; ++p) {
    int r = p * 16 + nLw;                        // row within chunk
    bG[0][p * 256 + sks * 64 + nLw * 4 + sq] = ebv[r * 16 + oct];
  }
  __syncthreads();

  unsigned int kmin[16];
  #pragma unroll
  for (int i = 0; i < 16; ++i) kmin[i] = 0xFFFFFFFFu;

  // ---- K loop: 16 chunks; this wave consumes its 2 jj-tiles (32 codes)
  #pragma unroll 1
  for (int ch = 0; ch < 16; ++ch) {
    const int cur = ch & 1;
    if (ch < 15) {                               // stage next chunk into !cur
      #pragma unroll
      for (int p = 0; p < 4; ++p) {
        int r = p * 16 + nLw;
        bG[cur ^ 1][p * 256 + sks * 64 + nLw * 4 + sq] =
            ebv[((ch + 1) * 64 + r) * 16 + oct];
      }
    }
    const short8* bp = (const short8*)bG[cur];
    #pragma unroll
    for (int j2 = 0; j2 < 2; ++j2) {
      const int jj = kh * 2 + j2;
      const int row = ch * 64 + jj * 16 + nL;    // this lane's code
      short8 b0 = bp[jj * 256 + 0 * 64 + nL * 4 + q];
      short8 b1 = bp[jj * 256 + 1 * 64 + nL * 4 + q];
      short8 b2 = bp[jj * 256 + 2 * 64 + nL * 4 + q];
      short8 b3 = bp[jj * 256 + 3 * 64 + nL * 4 + q];
      const float nv = nsq_s[row];
      f32x4 a0 = {nv, nv, nv, nv};
      f32x4 a1 = {nv, nv, nv, nv};
      f32x4 a2 = {nv, nv, nv, nv};
      f32x4 a3 = {nv, nv, nv, nv};
      a0 = __builtin_amdgcn_mfma_f32_16x16x32_bf16(afrag[0],  b0, a0, 0, 0, 0);
      a1 = __builtin_amdgcn_mfma_f32_16x16x32_bf16(afrag[4],  b0, a1, 0, 0, 0);
      a2 = __builtin_amdgcn_mfma_f32_16x16x32_bf16(afrag[8],  b0, a2, 0, 0, 0);
      a3 = __builtin_amdgcn_mfma_f32_16x16x32_bf16(afrag[12], b0, a3, 0, 0, 0);
      a0 = __builtin_amdgcn_mfma_f32_16x16x32_bf16(afrag[1],  b1, a0, 0, 0, 0);
      a1 = __builtin_amdgcn_mfma_f32_16x16x32_bf16(afrag[5],  b1, a1, 0, 0, 0);
      a2 = __builtin_amdgcn_mfma_f32_16x16x32_bf16(afrag[9],  b1, a2, 0, 0, 0);
      a3 = __builtin_amdgcn_mfma_f32_16x16x32_bf16(afrag[13], b1, a3, 0, 0, 0);
      a0 = __builtin_amdgcn_mfma_f32_16x16x32_bf16(afrag[2],  b2, a0, 0, 0, 0);
      a1 = __builtin_amdgcn_mfma_f32_16x16x32_bf16(afrag[6],  b2, a1, 0, 0, 0);
      a2 = __builtin_amdgcn_mfma_f32_16x16x32_bf16(afrag[10], b2, a2, 0, 0, 0);
      a3 = __builtin_amdgcn_mfma_f32_16x16x32_bf16(afrag[14], b2, a3, 0, 0, 0);
      a0 = __builtin_amdgcn_mfma_f32_16x16x32_bf16(afrag[3],  b3, a0, 0, 0, 0);
      a1 = __builtin_amdgcn_mfma_f32_16x16x32_bf16(afrag[7],  b3, a1, 0, 0, 0);
      a2 = __builtin_amdgcn_mfma_f32_16x16x32_bf16(afrag[11], b3, a2, 0, 0, 0);
      a3 = __builtin_amdgcn_mfma_f32_16x16x32_bf16(afrag[15], b3, a3, 0, 0, 0);
      const unsigned int rowc = (unsigned int)row;
      #pragma unroll
      for (int r = 0; r < 4; ++r) {
        unsigned int k0 = (__float_as_uint(a0[r]) & 0xFFFFFC00u) | rowc;
        if (k0 < kmin[r]) kmin[r] = k0;
        unsigned int k1 = (__float_as_uint(a1[r]) & 0xFFFFFC00u) | rowc;
        if (k1 < kmin[4 + r]) kmin[4 + r] = k1;
        unsigned int k2 = (__float_as_uint(a2[r]) & 0xFFFFFC00u) | rowc;
        if (k2 < kmin[8 + r]) kmin[8 + r] = k2;
        unsigned int k3 = (__float_as_uint(a3[r]) & 0xFFFFFC00u) | rowc;
        if (k3 < kmin[12 + r]) kmin[12 + r] = k3;
      }
    }
    __syncthreads();   // next-chunk writes visible; cur free for re-stage
  }

  // ---- in-wave butterfly u32-min over the 16 code-lanes of each quad
  #pragma unroll
  for (int m = 1; m <= 8; m <<= 1) {
    #pragma unroll
    for (int i = 0; i < 16; ++i) {
      unsigned int o = (unsigned int)__shfl_xor((int)kmin[i], m, 64);
      if (o < kmin[i]) kmin[i] = o;
    }
  }
  if (nL == 0) {
    #pragma unroll
    for (int mt = 0; mt < 4; ++mt)
      #pragma unroll
      for (int r = 0; r < 4; ++r)
        mergeK[ph * 64 + mt * 16 + q * 4 + r][kh] = kmin[mt * 4 + r];
  }
  __syncthreads();

  // ---- cross-half merge (2-way u32 min per pixel)
  if (t < 128) {
    unsigned int b = min(mergeK[t][0], mergeK[t][1]);
    int bi = (int)(b & 1023u);
    widx[t] = bi;
    used[bi] = 1;   // benign same-value race; kernel boundary = coherence
  }
  __syncthreads();

  // ---- gather bf16 e-row + coalesced z/out + loss partial
  float lsum = 0.f;
  {
    const int p = t & 127, cg = t >> 7;    // 2 channel halves x 64 ch
    const int idx = widx[p];
    const uint4* erow = ebv + idx * 16 + cg * 8;
    const int obase = zoff + cg * 64 * 4096 + p;
    #pragma unroll 2
    for (int i = 0; i < 8; ++i) {
      uint4 g = erow[i];
      const unsigned int wrd[4] = {g.x, g.y, g.z, g.w};
      #pragma unroll
      for (int half = 0; half < 4; ++half) {
        float e0 = __uint_as_float(wrd[half] << 16);
        float e1 = __uint_as_float(wrd[half] & 0xFFFF0000u);
        int off = obase + (i * 8 + half * 2) * 4096;
        float d0 = zin[off] - e0;
        out[off] = e0;                     // lanes over p -> 256B contiguous
        lsum += d0 * d0;
        off += 4096;
        float d1 = zin[off] - e1;
        out[off] = e1;
        lsum += d1 * d1;
      }
    }
  }
  #pragma unroll
  for (int o = 32; o > 0; o >>= 1) lsum += __shfl_down(lsum, o, 64);
  if (L == 0) wsum[wv] = lsum;
  __syncthreads();
  if (t == 0) lossp[blockIdx.x] = wsum[0] + wsum[1] + wsum[2] + wsum[3];
}

// ---- F: usage count + loss finalize ----
__global__ void finalize_kernel(const int* __restrict__ used,
                                const float* __restrict__ lossp,
                                float* __restrict__ out2) {
  __shared__ int   redi[256];
  __shared__ float redf[256];
  int t = threadIdx.x;
  int s = 0;
  for (int i = t; i < K_CODES; i += 256) s += (used[i] != 0) ? 1 : 0;
  float ls = 0.f;
  for (int i = t; i < NBLK; i += 256) ls += lossp[i];
  redi[t] = s; redf[t] = ls;
  __syncthreads();
  for (int o = 128; o > 0; o >>= 1) {
    if (t < o) { redi[t] += redi[t + o]; redf[t] += redf[t + o]; }
    __syncthreads();
  }
  if (t == 0) {
    out2[0] = 1.25f * redf[0] / (float)TOT;  // (1+0.25)*MSE
    out2[1] = (float)redi[0] / 1024.0f;
  }
}

extern "C" void kernel_launch(void* const* d_in, const int* in_sizes, int n_in,
                              void* d_out, int out_size, void* d_ws, size_t ws_size,
                              hipStream_t stream) {
  const float* z  = (const float*)d_in[0];
  const float* cb = (const float*)d_in[1];
  float* out = (float*)d_out;
  char* ws = (char*)d_ws;
  unsigned short* ebf = (unsigned short*)ws;          // 262144 B
  float* nsq1  = (float*)(ws + 262144);               // 4096 B
  int*   used  = (int*)(ws + 266240);                 // 4096 B
  float* lossp = (float*)(ws + 270336);               // 2048 B (per-block partials)

  hipLaunchKernelGGL(prep_kernel, dim3(128), dim3(256), 0, stream,
                     cb, ebf, nsq1, used);
  hipLaunchKernelGGL(vq_main, dim3(NBLK), dim3(256), 0, stream,
                     z, cb, ebf, nsq1, used, lossp, out);
  hipLaunchKernelGGL(finalize_kernel, dim3(1), dim3(256), 0, stream,
                     used, lossp, out + TOT);
}